// Round 15
// baseline (178.703 us; speedup 1.0000x reference)
//
#include <hip/hip_runtime.h>

#define N_NODES 100000
#define N_EDGES 1600000
#define F_IN    128
#define HID     128
#define F_OUT   64

#define NBUCK   196        // buckets of 512 nodes: dst>>9
#define NCHB    256        // chunk blocks for bucket hist/scatter
#define CHUNK_E (N_EDGES / NCHB)   // 6250 exactly
#define GHN     (NBUCK * NCHB)     // 50176 ghist entries
#define SCAN_BLKS (GHN / 256)      // 196 (exact)

#define XB_BLKS (N_NODES * 16 / 256)                  // 6250 (exact)
#define WC_BLKS ((HID * F_IN + F_OUT * HID + 255) / 256)  // 96

typedef __attribute__((ext_vector_type(8))) short bf16x8;
typedef __attribute__((ext_vector_type(8))) unsigned short u16x8;
typedef __attribute__((ext_vector_type(4))) float f32x4;

// ---------------- bf16 helpers ----------------

__device__ __forceinline__ unsigned int bf16rn(float f) {
    unsigned int u = __float_as_uint(f);
    return (u + 0x7fffu + ((u >> 16) & 1u)) >> 16;
}
__device__ __forceinline__ float bf16tof(unsigned short h) {
    return __uint_as_float(((unsigned int)h) << 16);
}

// ---------------- pre: xh convert + weight transpose + bucket histogram ----------------

__global__ __launch_bounds__(256) void k_pre(
        const float* __restrict__ x, unsigned short* __restrict__ xh,
        const float* __restrict__ W1, const float* __restrict__ W2,
        unsigned short* __restrict__ w1t, unsigned short* __restrict__ w2t,
        const int* __restrict__ dst, int* __restrict__ ghist) {
    __shared__ int bins[NBUCK];
    const int blk = blockIdx.x;
    const int t = threadIdx.x;
    if (blk < XB_BLKS) {
        int i = blk * 256 + t;
        float4 a = ((const float4*)x)[2 * i];
        float4 b = ((const float4*)x)[2 * i + 1];
        uint4 r;
        r.x = bf16rn(a.x) | (bf16rn(a.y) << 16);
        r.y = bf16rn(a.z) | (bf16rn(a.w) << 16);
        r.z = bf16rn(b.x) | (bf16rn(b.y) << 16);
        r.w = bf16rn(b.z) | (bf16rn(b.w) << 16);
        ((uint4*)xh)[i] = r;
    } else if (blk < XB_BLKS + WC_BLKS) {
        int i = (blk - XB_BLKS) * 256 + t;
        if (i < HID * F_IN) {
            int n = i >> 7, k = i & 127;
            w1t[i] = (unsigned short)bf16rn(W1[k * HID + n]);
        }
        int j = i - HID * F_IN;
        if (j >= 0 && j < F_OUT * HID) {
            int n = j >> 7, k = j & 127;
            w2t[j] = (unsigned short)bf16rn(W2[k * F_OUT + n]);
        }
    } else {
        int cb = blk - XB_BLKS - WC_BLKS;
        for (int j = t; j < NBUCK; j += 256) bins[j] = 0;
        __syncthreads();
        const int base = cb * CHUNK_E;
        for (int i = t; i < CHUNK_E; i += 256)
            atomicAdd(&bins[dst[base + i] >> 9], 1);
        __syncthreads();
        for (int j = t; j < NBUCK; j += 256)
            ghist[j * NCHB + cb] = bins[j];       // bucket-major
    }
}

// ---------------- single-kernel exclusive scan: ghist -> ghs (R11-proven) ----------------

__global__ __launch_bounds__(256) void k_scan(const int* __restrict__ ghist,
                                              int* __restrict__ ghs) {
    __shared__ int red[256];
    const int t = threadIdx.x;
    const int b = blockIdx.x;

    int s = 0;
    for (int i = t; i < b * 256; i += 256) s += ghist[i];
    red[t] = s;
    __syncthreads();
    for (int off = 128; off > 0; off >>= 1) {
        if (t < off) red[t] += red[t + off];
        __syncthreads();
    }
    const int base = red[0];
    __syncthreads();

    int v = ghist[b * 256 + t];
    red[t] = v;
    __syncthreads();
    for (int off = 1; off < 256; off <<= 1) {
        int u = (t >= off) ? red[t - off] : 0;
        __syncthreads();
        red[t] += u;
        __syncthreads();
    }
    ghs[b * 256 + t] = base + red[t] - v;         // exclusive
}

// ---------------- bucket scatter: LDS cursors, dlocal packed into bits 17..25 ----------------

__global__ __launch_bounds__(256) void k_bscatter(const int* __restrict__ src,
                                                  const int* __restrict__ dst,
                                                  const float* __restrict__ w,
                                                  const int* __restrict__ ghs,  // scanned
                                                  int2* __restrict__ spw) {
    __shared__ int cur[NBUCK];
    const int t = threadIdx.x;
    const int blk = blockIdx.x;
    for (int j = t; j < NBUCK; j += 256) cur[j] = ghs[j * NCHB + blk];
    __syncthreads();
    const int base = blk * CHUNK_E;
    for (int i = t; i < CHUNK_E; i += 256) {
        int e = base + i;
        int d = dst[e];
        int b = d >> 9;
        int pos = atomicAdd(&cur[b], 1);
        int2 p;
        p.x = src[e] | ((d & 511) << 17);     // src < 2^17
        p.y = __float_as_int(w[e]);
        spw[pos] = p;
    }
}

// ---------------- per-bucket CSR finalize: row_ptr, dinv, pairs ----------------

__global__ __launch_bounds__(512) void k_csr(const int2* __restrict__ spw,
                                             const int* __restrict__ ghs,   // scanned
                                             int* __restrict__ row_ptr,
                                             float* __restrict__ dinv,
                                             int2* __restrict__ pairs) {
    __shared__ int   scnt[512];
    __shared__ float swsum[512];
    __shared__ int   sexcl[512];
    const int t = threadIdx.x;
    const int b = blockIdx.x;
    const int bstart = ghs[b * NCHB];
    const int bend   = (b == NBUCK - 1) ? N_EDGES : ghs[(b + 1) * NCHB];
    const int ne = bend - bstart;

    scnt[t] = 0; swsum[t] = 0.0f;
    __syncthreads();
    for (int i = t; i < ne; i += 512) {
        int2 pe = spw[bstart + i];
        int dl = pe.x >> 17;
        atomicAdd(&scnt[dl], 1);
        atomicAdd(&swsum[dl], __int_as_float(pe.y));
    }
    __syncthreads();

    sexcl[t] = scnt[t];
    __syncthreads();
    for (int off = 1; off < 512; off <<= 1) {
        int u = (t >= off) ? sexcl[t - off] : 0;
        __syncthreads();
        sexcl[t] += u;
        __syncthreads();
    }
    int excl = sexcl[t] - scnt[t];

    int node = b * 512 + t;
    if (node < N_NODES) {
        row_ptr[node] = bstart + excl;
        dinv[node] = rsqrtf(1.0f + swsum[t]);
    }
    if (b == NBUCK - 1 && t == 0) row_ptr[N_NODES] = N_EDGES;

    sexcl[t] = excl;
    __syncthreads();
    scnt[t] = 0;
    __syncthreads();

    for (int i = t; i < ne; i += 512) {
        int2 pe = spw[bstart + i];
        int dl = pe.x >> 17;
        int r = atomicAdd(&scnt[dl], 1);
        int2 q;
        q.x = pe.x & 0x1FFFF;
        q.y = pe.y;
        pairs[bstart + sexcl[dl] + r] = q;
    }
}

// ---------------- gather-aggregate: 16 lanes/node, 16B loads, unroll-8 ----------------
// axh[n] = bf16( dn * ( dn*xh[n] + sum_e dinv[src]*w * xh[src] ) )

__global__ __launch_bounds__(256) void k_gather(const int2* __restrict__ pairs,
                                                const int* __restrict__ row_ptr,
                                                const float* __restrict__ dinv,
                                                const unsigned short* __restrict__ xh,
                                                unsigned short* __restrict__ axh) {
    int t = blockIdx.x * 256 + threadIdx.x;
    int n = t >> 4;                                // 16 lanes per node
    int lane = t & 15;                             // 8 bf16 (16B) per lane
    if (n >= N_NODES) return;

    const u16x8* xh8 = (const u16x8*)xh;
    float dn = dinv[n];
    u16x8 sv = xh8[n * 16 + lane];                 // self term
    float acc[8];
    #pragma unroll
    for (int j = 0; j < 8; ++j) acc[j] = dn * bf16tof(sv[j]);

    int beg = row_ptr[n];
    int end = row_ptr[n + 1];
    int e = beg;
    // unroll-8: eight independent 16B gathers in flight
    for (; e + 7 < end; e += 8) {
        int2 p[8];
        #pragma unroll
        for (int u = 0; u < 8; ++u) p[u] = pairs[e + u];
        float nw[8];
        #pragma unroll
        for (int u = 0; u < 8; ++u) nw[u] = dinv[p[u].x] * __int_as_float(p[u].y);
        u16x8 v[8];
        #pragma unroll
        for (int u = 0; u < 8; ++u) v[u] = xh8[p[u].x * 16 + lane];
        #pragma unroll
        for (int u = 0; u < 8; ++u) {
            #pragma unroll
            for (int j = 0; j < 8; ++j) acc[j] += nw[u] * bf16tof(v[u][j]);
        }
    }
    for (; e + 3 < end; e += 4) {
        int2 p[4];
        #pragma unroll
        for (int u = 0; u < 4; ++u) p[u] = pairs[e + u];
        float nw[4];
        #pragma unroll
        for (int u = 0; u < 4; ++u) nw[u] = dinv[p[u].x] * __int_as_float(p[u].y);
        u16x8 v[4];
        #pragma unroll
        for (int u = 0; u < 4; ++u) v[u] = xh8[p[u].x * 16 + lane];
        #pragma unroll
        for (int u = 0; u < 4; ++u) {
            #pragma unroll
            for (int j = 0; j < 8; ++j) acc[j] += nw[u] * bf16tof(v[u][j]);
        }
    }
    for (; e < end; ++e) {
        int2 p = pairs[e];
        float nw = dinv[p.x] * __int_as_float(p.y);
        u16x8 v = xh8[p.x * 16 + lane];
        #pragma unroll
        for (int j = 0; j < 8; ++j) acc[j] += nw * bf16tof(v[j]);
    }
    uint4 r;
    r.x = bf16rn(dn * acc[0]) | (bf16rn(dn * acc[1]) << 16);
    r.y = bf16rn(dn * acc[2]) | (bf16rn(dn * acc[3]) << 16);
    r.z = bf16rn(dn * acc[4]) | (bf16rn(dn * acc[5]) << 16);
    r.w = bf16rn(dn * acc[6]) | (bf16rn(dn * acc[7]) << 16);
    ((uint4*)axh)[n * 16 + lane] = r;
}

// ---------------- MFMA MLP: out = relu(axh@W1 + b1) @ W2 + b2 ----------------
// 64 rows/wave (4 row-tiles), 4 waves/block. B-fragments reused across 4 row-tiles.
// No __syncthreads (per-wave hbuf slice). C/D: col=lane&15, row=(lane>>4)*4+q.

__global__ __launch_bounds__(256) void k_mlp(
        const unsigned short* __restrict__ axh,   // [N][128] bf16
        const unsigned short* __restrict__ w1t,   // [128][128] bf16, w1t[n][k]
        const float* __restrict__ b1,
        const unsigned short* __restrict__ w2t,   // [64][128] bf16, w2t[n][k]
        const float* __restrict__ b2,
        float* __restrict__ out) {
    __shared__ unsigned short hbuf[4][64][128];   // per-wave 64-row h tile (64 KB)

    const int wid  = threadIdx.x >> 6;
    const int lane = threadIdx.x & 63;
    const int r = lane & 15;
    const int g = lane >> 4;
    const int swr = (r & 7) << 3;

    const int row0 = (blockIdx.x * 4 + wid) * 64;

    bool vld[4];
    int rbase[4];
    #pragma unroll
    for (int rt = 0; rt < 4; ++rt) {
        vld[rt] = (row0 + rt * 16 + 16 <= N_NODES);
        rbase[rt] = vld[rt] ? (row0 + rt * 16) : 0;
    }

    bf16x8 a1[4][4];
    #pragma unroll
    for (int rt = 0; rt < 4; ++rt) {
        const unsigned short* arow = axh + (size_t)(rbase[rt] + r) * HID + g * 8;
        #pragma unroll
        for (int kt = 0; kt < 4; ++kt)
            a1[rt][kt] = *(const bf16x8*)(arow + kt * 32);
    }

    // ---- layer 1: h[64][128] ----
    #pragma unroll
    for (int nt = 0; nt < 8; ++nt) {
        bf16x8 b[4];
        const unsigned short* bcol = w1t + (nt * 16 + r) * HID + g * 8;
        #pragma unroll
        for (int kt = 0; kt < 4; ++kt)
            b[kt] = *(const bf16x8*)(bcol + kt * 32);
        float bias = b1[nt * 16 + r];
        #pragma unroll
        for (int rt = 0; rt < 4; ++rt) {
            f32x4 acc = {0.f, 0.f, 0.f, 0.f};
            #pragma unroll
            for (int kt = 0; kt < 4; ++kt)
                acc = __builtin_amdgcn_mfma_f32_16x16x32_bf16(a1[rt][kt], b[kt], acc, 0, 0, 0);
            #pragma unroll
            for (int q = 0; q < 4; ++q) {
                int row16 = g * 4 + q;
                float v = fmaxf(acc[q] + bias, 0.0f);
                hbuf[wid][rt * 16 + row16][(nt * 16 + r) ^ ((row16 & 7) << 3)] =
                    (unsigned short)bf16rn(v);
            }
        }
    }

    bf16x8 a2[4][4];
    #pragma unroll
    for (int rt = 0; rt < 4; ++rt)
        #pragma unroll
        for (int kt = 0; kt < 4; ++kt)
            a2[rt][kt] = *(const bf16x8*)(&hbuf[wid][rt * 16 + r][(kt * 32 + g * 8) ^ swr]);

    // ---- layer 2: out[64][64] ----
    #pragma unroll
    for (int nt = 0; nt < 4; ++nt) {
        bf16x8 b[4];
        const unsigned short* bcol = w2t + (nt * 16 + r) * HID + g * 8;
        #pragma unroll
        for (int kt = 0; kt < 4; ++kt)
            b[kt] = *(const bf16x8*)(bcol + kt * 32);
        float bias = b2[nt * 16 + r];
        #pragma unroll
        for (int rt = 0; rt < 4; ++rt) {
            f32x4 acc = {0.f, 0.f, 0.f, 0.f};
            #pragma unroll
            for (int kt = 0; kt < 4; ++kt)
                acc = __builtin_amdgcn_mfma_f32_16x16x32_bf16(a2[rt][kt], b[kt], acc, 0, 0, 0);
            if (vld[rt]) {
                #pragma unroll
                for (int q = 0; q < 4; ++q)
                    out[(size_t)(row0 + rt * 16 + g * 4 + q) * F_OUT + nt * 16 + r] =
                        acc[q] + bias;
            }
        }
    }
}

// ---------------- launch ----------------

extern "C" void kernel_launch(void* const* d_in, const int* in_sizes, int n_in,
                              void* d_out, int out_size, void* d_ws, size_t ws_size,
                              hipStream_t stream) {
    const float* x  = (const float*)d_in[0];
    const int*   ei = (const int*)d_in[1];
    const float* ew = (const float*)d_in[2];
    const float* W1 = (const float*)d_in[3];
    const float* b1 = (const float*)d_in[4];
    const float* W2 = (const float*)d_in[5];
    const float* b2 = (const float*)d_in[6];
    float* out = (float*)d_out;

    const int* src = ei;
    const int* dst = ei + N_EDGES;

    // workspace layout — explicit 16B-aligned carve-out.
    // NOTE: axh aliases spw (spw dead after k_csr; axh written after, in k_gather).
    char* base = (char*)d_ws;
    auto alloc16 = [&](size_t bytes) { char* p = base; base += (bytes + 15) & ~(size_t)15; return p; };

    float*          dinv    = (float*)         alloc16(N_NODES * 4);
    unsigned short* xh      = (unsigned short*)alloc16((size_t)N_NODES * F_IN * 2);
    int*            row_ptr = (int*)           alloc16((N_NODES + 1) * 4);
    int*            ghist   = (int*)           alloc16(GHN * 4);
    int*            ghs     = (int*)           alloc16(GHN * 4);
    int2*           pairs   = (int2*)          alloc16((size_t)N_EDGES * 8);
    char*           big     =                  alloc16((size_t)N_NODES * HID * 2);  // 25.6MB >= E*8
    unsigned short* w1t     = (unsigned short*)alloc16(HID * F_IN * 2);
    unsigned short* w2t     = (unsigned short*)alloc16(F_OUT * HID * 2);

    int2*           spw     = (int2*)big;              // live: k_bscatter -> k_csr
    unsigned short* axh     = (unsigned short*)big;    // live: k_gather -> k_mlp

    k_pre<<<XB_BLKS + WC_BLKS + NCHB, 256, 0, stream>>>(x, xh, W1, W2, w1t, w2t, dst, ghist);
    k_scan<<<SCAN_BLKS, 256, 0, stream>>>(ghist, ghs);
    k_bscatter<<<NCHB, 256, 0, stream>>>(src, dst, ew, ghs, spw);
    k_csr<<<NBUCK, 512, 0, stream>>>(spw, ghs, row_ptr, dinv, pairs);
    k_gather<<<(N_NODES * 16 + 255) / 256, 256, 0, stream>>>(pairs, row_ptr, dinv, xh, axh);
    k_mlp<<<(N_NODES + 255) / 256, 256, 0, stream>>>(axh, w1t, b1, w2t, b2, out);
}

// Round 16
// 154.881 us; speedup vs baseline: 1.1538x; 1.1538x over previous
//
#include <hip/hip_runtime.h>

#define N_NODES 100000
#define N_EDGES 1600000
#define F_IN    128
#define HID     128
#define F_OUT   64

#define NBUCK   196        // buckets of 512 nodes: dst>>9
#define NCHB    256        // chunk blocks for bucket hist/scatter
#define CHUNK_E (N_EDGES / NCHB)   // 6250 exactly
#define GHN     (NBUCK * NCHB)     // 50176 ghist entries
#define GH_BLKS (GHN / 256)        // 196 (exact)

#define XB_BLKS (N_NODES * 16 / 256)                  // 6250 (exact)
#define WC_BLKS ((HID * F_IN + F_OUT * HID + 255) / 256)  // 96

typedef __attribute__((ext_vector_type(8))) short bf16x8;
typedef __attribute__((ext_vector_type(8))) unsigned short u16x8;
typedef __attribute__((ext_vector_type(4))) float f32x4;

// ---------------- bf16 helpers ----------------

__device__ __forceinline__ unsigned int bf16rn(float f) {
    unsigned int u = __float_as_uint(f);
    return (u + 0x7fffu + ((u >> 16) & 1u)) >> 16;
}
__device__ __forceinline__ float bf16tof(unsigned short h) {
    return __uint_as_float(((unsigned int)h) << 16);
}

// ---------------- pre: xh convert + weight transpose + bucket histogram ----------------

__global__ __launch_bounds__(256) void k_pre(
        const float* __restrict__ x, unsigned short* __restrict__ xh,
        const float* __restrict__ W1, const float* __restrict__ W2,
        unsigned short* __restrict__ w1t, unsigned short* __restrict__ w2t,
        const int* __restrict__ dst, int* __restrict__ ghist) {
    __shared__ int bins[NBUCK];
    const int blk = blockIdx.x;
    const int t = threadIdx.x;
    if (blk < XB_BLKS) {
        int i = blk * 256 + t;
        float4 a = ((const float4*)x)[2 * i];
        float4 b = ((const float4*)x)[2 * i + 1];
        uint4 r;
        r.x = bf16rn(a.x) | (bf16rn(a.y) << 16);
        r.y = bf16rn(a.z) | (bf16rn(a.w) << 16);
        r.z = bf16rn(b.x) | (bf16rn(b.y) << 16);
        r.w = bf16rn(b.z) | (bf16rn(b.w) << 16);
        ((uint4*)xh)[i] = r;
    } else if (blk < XB_BLKS + WC_BLKS) {
        int i = (blk - XB_BLKS) * 256 + t;
        if (i < HID * F_IN) {
            int n = i >> 7, k = i & 127;
            w1t[i] = (unsigned short)bf16rn(W1[k * HID + n]);
        }
        int j = i - HID * F_IN;
        if (j >= 0 && j < F_OUT * HID) {
            int n = j >> 7, k = j & 127;
            w2t[j] = (unsigned short)bf16rn(W2[k * F_OUT + n]);
        }
    } else {
        int cb = blk - XB_BLKS - WC_BLKS;
        for (int j = t; j < NBUCK; j += 256) bins[j] = 0;
        __syncthreads();
        const int base = cb * CHUNK_E;
        for (int i = t; i < CHUNK_E; i += 256)
            atomicAdd(&bins[dst[base + i] >> 9], 1);
        __syncthreads();
        for (int j = t; j < NBUCK; j += 256)
            ghist[j * NCHB + cb] = bins[j];       // bucket-major
    }
}

// ---------------- 2-level exclusive scan ----------------
// part[b] = sum of ghist chunk b (196 blocks)

__global__ void k_scan_part(const int* __restrict__ data, int* __restrict__ part, int n) {
    int i = blockIdx.x * 256 + threadIdx.x;
    int v = (i < n) ? data[i] : 0;
    #pragma unroll
    for (int off = 32; off > 0; off >>= 1) v += __shfl_down(v, off, 64);
    __shared__ int ws[4];
    if ((threadIdx.x & 63) == 0) ws[threadIdx.x >> 6] = v;
    __syncthreads();
    if (threadIdx.x == 0) part[blockIdx.x] = ws[0] + ws[1] + ws[2] + ws[3];
}

// each block: LDS-scan the 196 partials (O(nparts) work) -> base, then scan own chunk in-place
__global__ __launch_bounds__(256) void k_scan_down2(int* __restrict__ data,
                                                    const int* __restrict__ part,
                                                    int n, int nparts) {
    __shared__ int red[256];
    const int t = threadIdx.x;
    const int b = blockIdx.x;

    red[t] = (t < nparts) ? part[t] : 0;
    __syncthreads();
    for (int off = 1; off < 256; off <<= 1) {
        int u = (t >= off) ? red[t - off] : 0;
        __syncthreads();
        red[t] += u;
        __syncthreads();
    }
    const int base = (b == 0) ? 0 : red[b - 1];   // exclusive sum of partials < b
    __syncthreads();

    int i = b * 256 + t;
    int v = (i < n) ? data[i] : 0;
    red[t] = v;
    __syncthreads();
    for (int off = 1; off < 256; off <<= 1) {
        int u = (t >= off) ? red[t - off] : 0;
        __syncthreads();
        red[t] += u;
        __syncthreads();
    }
    if (i < n) data[i] = base + red[t] - v;       // exclusive, in place
}

// ---------------- bucket scatter: LDS cursors, dlocal packed into bits 17..25 ----------------

__global__ __launch_bounds__(256) void k_bscatter(const int* __restrict__ src,
                                                  const int* __restrict__ dst,
                                                  const float* __restrict__ w,
                                                  const int* __restrict__ ghist,  // scanned
                                                  int2* __restrict__ spw) {
    __shared__ int cur[NBUCK];
    const int t = threadIdx.x;
    const int blk = blockIdx.x;
    for (int j = t; j < NBUCK; j += 256) cur[j] = ghist[j * NCHB + blk];
    __syncthreads();
    const int base = blk * CHUNK_E;
    for (int i = t; i < CHUNK_E; i += 256) {
        int e = base + i;
        int d = dst[e];
        int b = d >> 9;
        int pos = atomicAdd(&cur[b], 1);
        int2 p;
        p.x = src[e] | ((d & 511) << 17);     // src < 2^17
        p.y = __float_as_int(w[e]);
        spw[pos] = p;
    }
}

// ---------------- per-bucket CSR finalize: row_ptr, dinv, pairs ----------------

__global__ __launch_bounds__(512) void k_csr(const int2* __restrict__ spw,
                                             const int* __restrict__ ghist,   // scanned
                                             int* __restrict__ row_ptr,
                                             float* __restrict__ dinv,
                                             int2* __restrict__ pairs) {
    __shared__ int   scnt[512];
    __shared__ float swsum[512];
    __shared__ int   sexcl[512];
    const int t = threadIdx.x;
    const int b = blockIdx.x;
    const int bstart = ghist[b * NCHB];
    const int bend   = (b == NBUCK - 1) ? N_EDGES : ghist[(b + 1) * NCHB];
    const int ne = bend - bstart;

    scnt[t] = 0; swsum[t] = 0.0f;
    __syncthreads();
    for (int i = t; i < ne; i += 512) {
        int2 pe = spw[bstart + i];
        int dl = pe.x >> 17;
        atomicAdd(&scnt[dl], 1);
        atomicAdd(&swsum[dl], __int_as_float(pe.y));
    }
    __syncthreads();

    sexcl[t] = scnt[t];
    __syncthreads();
    for (int off = 1; off < 512; off <<= 1) {
        int u = (t >= off) ? sexcl[t - off] : 0;
        __syncthreads();
        sexcl[t] += u;
        __syncthreads();
    }
    int excl = sexcl[t] - scnt[t];

    int node = b * 512 + t;
    if (node < N_NODES) {
        row_ptr[node] = bstart + excl;
        dinv[node] = rsqrtf(1.0f + swsum[t]);
    }
    if (b == NBUCK - 1 && t == 0) row_ptr[N_NODES] = N_EDGES;

    sexcl[t] = excl;
    __syncthreads();
    scnt[t] = 0;
    __syncthreads();

    for (int i = t; i < ne; i += 512) {
        int2 pe = spw[bstart + i];
        int dl = pe.x >> 17;
        int r = atomicAdd(&scnt[dl], 1);
        int2 q;
        q.x = pe.x & 0x1FFFF;
        q.y = pe.y;
        pairs[bstart + sexcl[dl] + r] = q;
    }
}

// ---------------- gather-aggregate: 16 lanes/node, 16B loads, unroll-4 (R14-proven) ----------------
// axh[n] = bf16( dn * ( dn*xh[n] + sum_e dinv[src]*w * xh[src] ) )

__global__ __launch_bounds__(256) void k_gather(const int2* __restrict__ pairs,
                                                const int* __restrict__ row_ptr,
                                                const float* __restrict__ dinv,
                                                const unsigned short* __restrict__ xh,
                                                unsigned short* __restrict__ axh) {
    int t = blockIdx.x * 256 + threadIdx.x;
    int n = t >> 4;                                // 16 lanes per node
    int lane = t & 15;                             // 8 bf16 (16B) per lane
    if (n >= N_NODES) return;

    const u16x8* xh8 = (const u16x8*)xh;
    float dn = dinv[n];
    u16x8 sv = xh8[n * 16 + lane];                 // self term
    float acc[8];
    #pragma unroll
    for (int j = 0; j < 8; ++j) acc[j] = dn * bf16tof(sv[j]);

    int beg = row_ptr[n];
    int end = row_ptr[n + 1];
    int e = beg;
    for (; e + 3 < end; e += 4) {                  // 4 independent 16B gathers in flight
        int2 p0 = pairs[e];
        int2 p1 = pairs[e + 1];
        int2 p2 = pairs[e + 2];
        int2 p3 = pairs[e + 3];
        float nw0 = dinv[p0.x] * __int_as_float(p0.y);
        float nw1 = dinv[p1.x] * __int_as_float(p1.y);
        float nw2 = dinv[p2.x] * __int_as_float(p2.y);
        float nw3 = dinv[p3.x] * __int_as_float(p3.y);
        u16x8 v0 = xh8[p0.x * 16 + lane];
        u16x8 v1 = xh8[p1.x * 16 + lane];
        u16x8 v2 = xh8[p2.x * 16 + lane];
        u16x8 v3 = xh8[p3.x * 16 + lane];
        #pragma unroll
        for (int j = 0; j < 8; ++j) acc[j] += nw0 * bf16tof(v0[j]);
        #pragma unroll
        for (int j = 0; j < 8; ++j) acc[j] += nw1 * bf16tof(v1[j]);
        #pragma unroll
        for (int j = 0; j < 8; ++j) acc[j] += nw2 * bf16tof(v2[j]);
        #pragma unroll
        for (int j = 0; j < 8; ++j) acc[j] += nw3 * bf16tof(v3[j]);
    }
    for (; e < end; ++e) {
        int2 p = pairs[e];
        float nw = dinv[p.x] * __int_as_float(p.y);
        u16x8 v = xh8[p.x * 16 + lane];
        #pragma unroll
        for (int j = 0; j < 8; ++j) acc[j] += nw * bf16tof(v[j]);
    }
    uint4 r;
    r.x = bf16rn(dn * acc[0]) | (bf16rn(dn * acc[1]) << 16);
    r.y = bf16rn(dn * acc[2]) | (bf16rn(dn * acc[3]) << 16);
    r.z = bf16rn(dn * acc[4]) | (bf16rn(dn * acc[5]) << 16);
    r.w = bf16rn(dn * acc[6]) | (bf16rn(dn * acc[7]) << 16);
    ((uint4*)axh)[n * 16 + lane] = r;
}

// ---------------- MFMA MLP: out = relu(axh@W1 + b1) @ W2 + b2 ----------------
// 64 rows/wave (4 row-tiles), 4 waves/block. B-fragments reused across 4 row-tiles.
// No __syncthreads (per-wave hbuf slice). C/D: col=lane&15, row=(lane>>4)*4+q.

__global__ __launch_bounds__(256) void k_mlp(
        const unsigned short* __restrict__ axh,   // [N][128] bf16
        const unsigned short* __restrict__ w1t,   // [128][128] bf16, w1t[n][k]
        const float* __restrict__ b1,
        const unsigned short* __restrict__ w2t,   // [64][128] bf16, w2t[n][k]
        const float* __restrict__ b2,
        float* __restrict__ out) {
    __shared__ unsigned short hbuf[4][64][128];   // per-wave 64-row h tile (64 KB)

    const int wid  = threadIdx.x >> 6;
    const int lane = threadIdx.x & 63;
    const int r = lane & 15;
    const int g = lane >> 4;
    const int swr = (r & 7) << 3;

    const int row0 = (blockIdx.x * 4 + wid) * 64;

    bool vld[4];
    int rbase[4];
    #pragma unroll
    for (int rt = 0; rt < 4; ++rt) {
        vld[rt] = (row0 + rt * 16 + 16 <= N_NODES);
        rbase[rt] = vld[rt] ? (row0 + rt * 16) : 0;
    }

    bf16x8 a1[4][4];
    #pragma unroll
    for (int rt = 0; rt < 4; ++rt) {
        const unsigned short* arow = axh + (size_t)(rbase[rt] + r) * HID + g * 8;
        #pragma unroll
        for (int kt = 0; kt < 4; ++kt)
            a1[rt][kt] = *(const bf16x8*)(arow + kt * 32);
    }

    // ---- layer 1: h[64][128] ----
    #pragma unroll
    for (int nt = 0; nt < 8; ++nt) {
        bf16x8 b[4];
        const unsigned short* bcol = w1t + (nt * 16 + r) * HID + g * 8;
        #pragma unroll
        for (int kt = 0; kt < 4; ++kt)
            b[kt] = *(const bf16x8*)(bcol + kt * 32);
        float bias = b1[nt * 16 + r];
        #pragma unroll
        for (int rt = 0; rt < 4; ++rt) {
            f32x4 acc = {0.f, 0.f, 0.f, 0.f};
            #pragma unroll
            for (int kt = 0; kt < 4; ++kt)
                acc = __builtin_amdgcn_mfma_f32_16x16x32_bf16(a1[rt][kt], b[kt], acc, 0, 0, 0);
            #pragma unroll
            for (int q = 0; q < 4; ++q) {
                int row16 = g * 4 + q;
                float v = fmaxf(acc[q] + bias, 0.0f);
                hbuf[wid][rt * 16 + row16][(nt * 16 + r) ^ ((row16 & 7) << 3)] =
                    (unsigned short)bf16rn(v);
            }
        }
    }

    bf16x8 a2[4][4];
    #pragma unroll
    for (int rt = 0; rt < 4; ++rt)
        #pragma unroll
        for (int kt = 0; kt < 4; ++kt)
            a2[rt][kt] = *(const bf16x8*)(&hbuf[wid][rt * 16 + r][(kt * 32 + g * 8) ^ swr]);

    // ---- layer 2: out[64][64] ----
    #pragma unroll
    for (int nt = 0; nt < 4; ++nt) {
        bf16x8 b[4];
        const unsigned short* bcol = w2t + (nt * 16 + r) * HID + g * 8;
        #pragma unroll
        for (int kt = 0; kt < 4; ++kt)
            b[kt] = *(const bf16x8*)(bcol + kt * 32);
        float bias = b2[nt * 16 + r];
        #pragma unroll
        for (int rt = 0; rt < 4; ++rt) {
            f32x4 acc = {0.f, 0.f, 0.f, 0.f};
            #pragma unroll
            for (int kt = 0; kt < 4; ++kt)
                acc = __builtin_amdgcn_mfma_f32_16x16x32_bf16(a2[rt][kt], b[kt], acc, 0, 0, 0);
            if (vld[rt]) {
                #pragma unroll
                for (int q = 0; q < 4; ++q)
                    out[(size_t)(row0 + rt * 16 + g * 4 + q) * F_OUT + nt * 16 + r] =
                        acc[q] + bias;
            }
        }
    }
}

// ---------------- launch ----------------

extern "C" void kernel_launch(void* const* d_in, const int* in_sizes, int n_in,
                              void* d_out, int out_size, void* d_ws, size_t ws_size,
                              hipStream_t stream) {
    const float* x  = (const float*)d_in[0];
    const int*   ei = (const int*)d_in[1];
    const float* ew = (const float*)d_in[2];
    const float* W1 = (const float*)d_in[3];
    const float* b1 = (const float*)d_in[4];
    const float* W2 = (const float*)d_in[5];
    const float* b2 = (const float*)d_in[6];
    float* out = (float*)d_out;

    const int* src = ei;
    const int* dst = ei + N_EDGES;

    // workspace layout — explicit 16B-aligned carve-out.
    // NOTE: axh aliases spw (spw dead after k_csr; axh written after, in k_gather).
    char* base = (char*)d_ws;
    auto alloc16 = [&](size_t bytes) { char* p = base; base += (bytes + 15) & ~(size_t)15; return p; };

    float*          dinv    = (float*)         alloc16(N_NODES * 4);
    unsigned short* xh      = (unsigned short*)alloc16((size_t)N_NODES * F_IN * 2);
    int*            row_ptr = (int*)           alloc16((N_NODES + 1) * 4);
    int*            ghist   = (int*)           alloc16(GHN * 4);
    int*            part    = (int*)           alloc16(256 * 4);
    int2*           pairs   = (int2*)          alloc16((size_t)N_EDGES * 8);
    char*           big     =                  alloc16((size_t)N_NODES * HID * 2);  // 25.6MB >= E*8
    unsigned short* w1t     = (unsigned short*)alloc16(HID * F_IN * 2);
    unsigned short* w2t     = (unsigned short*)alloc16(F_OUT * HID * 2);

    int2*           spw     = (int2*)big;              // live: k_bscatter -> k_csr
    unsigned short* axh     = (unsigned short*)big;    // live: k_gather -> k_mlp

    k_pre<<<XB_BLKS + WC_BLKS + NCHB, 256, 0, stream>>>(x, xh, W1, W2, w1t, w2t, dst, ghist);
    k_scan_part<<<GH_BLKS, 256, 0, stream>>>(ghist, part, GHN);
    k_scan_down2<<<GH_BLKS, 256, 0, stream>>>(ghist, part, GHN, GH_BLKS);
    k_bscatter<<<NCHB, 256, 0, stream>>>(src, dst, ew, ghist, spw);
    k_csr<<<NBUCK, 512, 0, stream>>>(spw, ghist, row_ptr, dinv, pairs);
    k_gather<<<(N_NODES * 16 + 255) / 256, 256, 0, stream>>>(pairs, row_ptr, dinv, xh, axh);
    k_mlp<<<(N_NODES + 255) / 256, 256, 0, stream>>>(axh, w1t, b1, w2t, b2, out);
}